// Round 12
// baseline (52.161 us; speedup 1.0000x reference)
//
#include <hip/hip_runtime.h>

// RegionAttention: bin 8M landmarks into a 512x512 grid; out[i] = enhanced[i]
// if any landmark falls in bin i else 1.0f.
//
// Round 12: hand-rolled single-kernel fusion. R9 split: bin+gap=12.05us,
// merge+fixed=8us -> slack is the dispatch boundary (drain+WBINV+ramp), not
// execution. R6's cooperative fusion failed because cg::sync() is a real call
// (ABI forced VGPR=16, buf[16] demoted to scratch); hand-rolled barrier keeps
// the R5 bin body in registers. 256 blocks x 1024 thr = 1 block/CU -> all
// co-resident, spin is deadlock-safe. Counter zeroed per call via 4B
// hipMemsetAsync (deterministic, capture-legal).
// Ledger: R4 occ null | R5 MLP null | R6 coop -45 | R7 width null |
// R8 g-atomics -7 | R9 diag | R10/11 NT null.

#define N_LANDMARKS 8388608
#define N_BINS      262144            // 512*512
#define GRID_COLS   512
#define NWORDS      (N_BINS / 32)     // 8192 dwords = 32 KB bitmask
#define NBLK        256
#define NTHR        1024
#define ITERS       16                // (N_LANDMARKS/2) / (NBLK*NTHR) exactly
#define WPB         (NWORDS / NBLK)   // 32 merge words per block

__global__ __launch_bounds__(NTHR)
void fused_kernel(const float4* __restrict__ lm2,
                  const float* __restrict__ ew,
                  float* __restrict__ out,
                  unsigned int* __restrict__ regions,
                  unsigned int* __restrict__ counter) {
    __shared__ unsigned int mask[NWORDS];      // 32 KB
    __shared__ unsigned int part[32][33];      // 4.2 KB, +1 pad
    __shared__ unsigned int merged[WPB];

    const int tid = threadIdx.x;
    const int b   = blockIdx.x;

    // --- init mask ---
    uint4* mask4 = (uint4*)mask;
    #pragma unroll
    for (int w = tid; w < NWORDS / 4; w += NTHR)
        mask4[w] = make_uint4(0u, 0u, 0u, 0u);
    __syncthreads();

    // --- bin: R5 body (16 loads up front, statically indexed -> registers) ---
    const int total = NBLK * NTHR;             // 262144 threads
    const int base  = b * NTHR + tid;
    float4 buf[ITERS];
    #pragma unroll
    for (int k = 0; k < ITERS; ++k)
        buf[k] = lm2[base + k * total];

    #pragma unroll
    for (int k = 0; k < ITERS; ++k) {
        float4 v = buf[k];                     // (x0,y0,x1,y1)
        int c0 = min((int)(v.x * 0.0625f), GRID_COLS - 1);
        int r0 = min((int)(v.y * 0.0625f), GRID_COLS - 1);
        int c1 = min((int)(v.z * 0.0625f), GRID_COLS - 1);
        int r1 = min((int)(v.w * 0.0625f), GRID_COLS - 1);
        unsigned int i0 = (unsigned int)(r0 * GRID_COLS + c0);
        unsigned int i1 = (unsigned int)(r1 * GRID_COLS + c1);
        atomicOr(&mask[i0 >> 5], 1u << (i0 & 31));   // ds_or_b32, no return
        atomicOr(&mask[i1 >> 5], 1u << (i1 & 31));
    }
    __syncthreads();

    // --- dump LDS mask -> per-block region (coalesced dwordx4) ---
    uint4* dst4 = (uint4*)(regions + (size_t)b * NWORDS);
    #pragma unroll
    for (int w = tid; w < NWORDS / 4; w += NTHR)
        dst4[w] = mask4[w];

    // --- hand-rolled grid barrier (no CG call: registers stay live) ---
    __syncthreads();                           // all dump stores drained (vmcnt 0)
    if (tid == 0) {
        __threadfence();                       // release: write back XCD L2
        atomicAdd(counter, 1u);                // device-scope arrive
        while (__hip_atomic_load(counter, __ATOMIC_RELAXED,
                                 __HIP_MEMORY_SCOPE_AGENT) < NBLK) {
            __builtin_amdgcn_s_sleep(8);
        }
        __threadfence();                       // acquire: invalidate stale caches
    }
    __syncthreads();

    // --- merge: block owns words [b*WPB, (b+1)*WPB) = 1024 bins ---
    const int wl  = tid & 31;                  // word within block
    const int seg = tid >> 5;                  // 0..31; ORs regions seg*8..seg*8+7
    const unsigned int* p = regions + (size_t)(seg * 8) * NWORDS + b * WPB + wl;
    unsigned int m = 0u;
    #pragma unroll
    for (int j = 0; j < 8; ++j)
        m |= p[(size_t)j * NWORDS];
    part[seg][wl] = m;
    __syncthreads();

    if (tid < WPB) {
        unsigned int mm = part[0][tid];
        #pragma unroll
        for (int s = 1; s < 32; ++s) mm |= part[s][tid];
        merged[tid] = mm;
    }
    __syncthreads();

    // --- blend: 1024 bins/block, coalesced ---
    const int g = b * NTHR + tid;
    const unsigned int mw = merged[tid >> 5];
    out[g] = ((mw >> (tid & 31)) & 1u) ? ew[g] : 1.0f;
}

// --- fallback: R5 two-kernel path (if ws unexpectedly small) ------------------

__global__ __launch_bounds__(NTHR)
void bin_lds_kernel(const float4* __restrict__ lm2,
                    unsigned int* __restrict__ regions) {
    __shared__ unsigned int mask[NWORDS];
    const int tid = threadIdx.x;
    #pragma unroll
    for (int w = tid; w < NWORDS; w += NTHR) mask[w] = 0u;
    __syncthreads();
    const int total = NBLK * NTHR;
    const int base  = blockIdx.x * NTHR + tid;
    float4 buf[ITERS];
    #pragma unroll
    for (int k = 0; k < ITERS; ++k) buf[k] = lm2[base + k * total];
    #pragma unroll
    for (int k = 0; k < ITERS; ++k) {
        float4 v = buf[k];
        int c0 = min((int)(v.x * 0.0625f), GRID_COLS - 1);
        int r0 = min((int)(v.y * 0.0625f), GRID_COLS - 1);
        int c1 = min((int)(v.z * 0.0625f), GRID_COLS - 1);
        int r1 = min((int)(v.w * 0.0625f), GRID_COLS - 1);
        unsigned int i0 = (unsigned int)(r0 * GRID_COLS + c0);
        unsigned int i1 = (unsigned int)(r1 * GRID_COLS + c1);
        atomicOr(&mask[i0 >> 5], 1u << (i0 & 31));
        atomicOr(&mask[i1 >> 5], 1u << (i1 & 31));
    }
    __syncthreads();
    unsigned int* dst = regions + (size_t)blockIdx.x * NWORDS;
    #pragma unroll
    for (int w = tid; w < NWORDS; w += NTHR) dst[w] = mask[w];
}

__global__ __launch_bounds__(256)
void merge_blend_kernel(const unsigned int* __restrict__ regions,
                        const float4* __restrict__ ew4,
                        float4* __restrict__ out4) {
    __shared__ unsigned int part[8][33];
    __shared__ unsigned int merged[32];
    const int t   = threadIdx.x;
    const int wl  = t & 31;
    const int seg = t >> 5;
    const int w   = blockIdx.x * 32 + wl;
    const unsigned int* p = regions + (size_t)seg * 32 * NWORDS + w;
    unsigned int m = 0u;
    #pragma unroll
    for (int bb = 0; bb < 32; ++bb) m |= p[(size_t)bb * NWORDS];
    part[seg][wl] = m;
    __syncthreads();
    if (t < 32) {
        unsigned int mm = part[0][t];
        #pragma unroll
        for (int s = 1; s < 8; ++s) mm |= part[s][t];
        merged[t] = mm;
    }
    __syncthreads();
    const int g4 = blockIdx.x * 256 + t;
    const unsigned int mw = merged[t >> 3];
    const int sh = (t & 7) * 4;
    float4 e = ew4[g4];
    float4 r;
    r.x = ((mw >> (sh + 0)) & 1u) ? e.x : 1.0f;
    r.y = ((mw >> (sh + 1)) & 1u) ? e.y : 1.0f;
    r.z = ((mw >> (sh + 2)) & 1u) ? e.z : 1.0f;
    r.w = ((mw >> (sh + 3)) & 1u) ? e.w : 1.0f;
    out4[g4] = r;
}

extern "C" void kernel_launch(void* const* d_in, const int* in_sizes, int n_in,
                              void* d_out, int out_size, void* d_ws, size_t ws_size,
                              hipStream_t stream) {
    const float4* lm2 = (const float4*)d_in[0];
    const float*  ew  = (const float*)d_in[1];
    float* out        = (float*)d_out;

    const size_t need = 4096 + (size_t)NBLK * NWORDS * sizeof(unsigned int); // 4K + 8MB

    if (ws_size >= need) {
        unsigned int* counter = (unsigned int*)d_ws;
        unsigned int* regions = (unsigned int*)((char*)d_ws + 4096);
        hipMemsetAsync(counter, 0, sizeof(unsigned int), stream);
        fused_kernel<<<NBLK, NTHR, 0, stream>>>(lm2, ew, out, regions, counter);
    } else {
        unsigned int* regions = (unsigned int*)d_ws;
        bin_lds_kernel<<<NBLK, NTHR, 0, stream>>>(lm2, regions);
        merge_blend_kernel<<<NWORDS / 32, 256, 0, stream>>>(
            regions, (const float4*)ew, (float4*)out);
    }
    (void)in_sizes; (void)n_in; (void)out_size;
}

// Round 13
// 26.996 us; speedup vs baseline: 1.9322x; 1.9322x over previous
//
#include <hip/hip_runtime.h>

// RegionAttention: bin 8M landmarks into a 512x512 grid; out[i] = enhanced[i]
// if any landmark falls in bin i else 1.0f.
//
// Round 13: fence-free single-dispatch fusion. R12==R6 (identical counters)
// proved the fusion cost is the per-block agent-scope threadfence pair
// (buffer_wbl2 + buffer_inv per block = ~32 serialized L2 flushes per XCD),
// not the barrier and not cg. This variant has ZERO threadfences:
//  - region dump via agent-scope RELAXED ATOMIC STORES (write-through to the
//    MALL coherence point; plain stores, not RMW -> full BW, unlike R8)
//  - __syncthreads() drains vmcnt(0) in every wave (documented codegen) so
//    dumps are globally visible before tid0's rank atomicAdd
//  - last-K: ranks 0..127 exit; ranks 128..255 spin (relaxed, s_sleep) until
//    counter==256, then merge a 64-word slice + blend 2048 bins each.
//  Stale-L2 impossible: dispatch-start invalidate + write-through dumps mean
//  local L2 holds only clean current-dispatch lines.
// Ledger: R4 occ null | R5 MLP null | R6 coop -45 | R7 width null |
// R8 g-atomic-RMW -7 | R9 diag bin+gap=12.05 | R10/11 NT null | R12 fences -32.

#define N_LANDMARKS 8388608
#define N_BINS      262144            // 512*512
#define GRID_COLS   512
#define NWORDS      (N_BINS / 32)     // 8192 dwords = 32 KB bitmask
#define NQW         (NWORDS / 2)      // 4096 qwords per region
#define NBLK        256
#define NTHR        1024
#define ITERS       16                // (N_LANDMARKS/2) / (NBLK*NTHR) exactly
#define KMERGE      128               // last-K blocks do the merge
#define WSLICE      (NWORDS / KMERGE) // 64 words per merge block

__global__ __launch_bounds__(NTHR)
void fused_kernel(const float4* __restrict__ lm2,
                  const float* __restrict__ ew,
                  float* __restrict__ out,
                  unsigned int* __restrict__ regions,
                  unsigned int* __restrict__ counter) {
    __shared__ unsigned int mask[NWORDS];      // 32 KB
    __shared__ unsigned int part[16][65];      // 4.2 KB, +1 pad
    __shared__ unsigned int merged[WSLICE];    // 256 B
    __shared__ unsigned int rank_s;

    const int tid = threadIdx.x;
    const int b   = blockIdx.x;

    // --- init mask ---
    uint4* mask4 = (uint4*)mask;
    #pragma unroll
    for (int w = tid; w < NWORDS / 4; w += NTHR)
        mask4[w] = make_uint4(0u, 0u, 0u, 0u);
    __syncthreads();

    // --- bin: R5 body (16 loads up front, statically indexed -> registers) ---
    const int total = NBLK * NTHR;             // 262144 threads
    const int base  = b * NTHR + tid;
    float4 buf[ITERS];
    #pragma unroll
    for (int k = 0; k < ITERS; ++k)
        buf[k] = lm2[base + k * total];

    #pragma unroll
    for (int k = 0; k < ITERS; ++k) {
        float4 v = buf[k];                     // (x0,y0,x1,y1)
        int c0 = min((int)(v.x * 0.0625f), GRID_COLS - 1);
        int r0 = min((int)(v.y * 0.0625f), GRID_COLS - 1);
        int c1 = min((int)(v.z * 0.0625f), GRID_COLS - 1);
        int r1 = min((int)(v.w * 0.0625f), GRID_COLS - 1);
        unsigned int i0 = (unsigned int)(r0 * GRID_COLS + c0);
        unsigned int i1 = (unsigned int)(r1 * GRID_COLS + c1);
        atomicOr(&mask[i0 >> 5], 1u << (i0 & 31));   // ds_or_b32, no return
        atomicOr(&mask[i1 >> 5], 1u << (i1 & 31));
    }
    __syncthreads();

    // --- dump: agent-scope relaxed atomic stores (write-through, no dirty L2,
    //     no RMW). 4 qword stores/thread, wave-contiguous. ---
    unsigned long long* dst = (unsigned long long*)(regions + (size_t)b * NWORDS);
    const unsigned long long* src = (const unsigned long long*)mask;
    #pragma unroll
    for (int q = tid; q < NQW; q += NTHR)
        __hip_atomic_store(&dst[q], src[q], __ATOMIC_RELAXED,
                           __HIP_MEMORY_SCOPE_AGENT);

    // __syncthreads drains vmcnt(0) in EVERY wave -> all dumps globally
    // visible (write-through) before the rank increment below. No fence.
    __syncthreads();

    if (tid == 0)
        rank_s = atomicAdd(counter, 1u);       // arrival rank, device scope
    __syncthreads();

    const unsigned int rank = rank_s;
    if (rank < NBLK - KMERGE)
        return;                                // early blocks: done

    // --- last-K blocks: wait for all arrivals (relaxed spin), then merge ---
    if (tid == 0) {
        while (__hip_atomic_load(counter, __ATOMIC_RELAXED,
                                 __HIP_MEMORY_SCOPE_AGENT) < NBLK)
            __builtin_amdgcn_s_sleep(2);
    }
    __syncthreads();

    // merge slice: words [slice*WSLICE, (slice+1)*WSLICE)
    const int slice = (int)rank - (NBLK - KMERGE); // 0..127
    const int wl    = tid & 63;                    // word within slice
    const int seg   = tid >> 6;                    // 0..15, ORs 16 regions each
    const int wbase = slice * WSLICE;

    const unsigned int* p = regions + (size_t)(seg * 16) * NWORDS + wbase + wl;
    unsigned int m = 0u;
    #pragma unroll
    for (int j = 0; j < 16; ++j)
        m |= p[(size_t)j * NWORDS];
    part[seg][wl] = m;
    __syncthreads();

    if (tid < WSLICE) {
        unsigned int mm = part[0][tid];
        #pragma unroll
        for (int s = 1; s < 16; ++s) mm |= part[s][tid];
        merged[tid] = mm;
    }
    __syncthreads();

    // blend: 2048 bins = 1024 float2; thread t -> bins 2t, 2t+1 (local)
    const int g2 = (wbase << 4) + tid;             // global float2 index
    const unsigned int mw = merged[tid >> 4];
    const int sh = (tid & 15) * 2;
    const float2* ew2 = (const float2*)ew;
    float2* out2 = (float2*)out;
    float2 e = ew2[g2];
    float2 r;
    r.x = ((mw >> (sh + 0)) & 1u) ? e.x : 1.0f;
    r.y = ((mw >> (sh + 1)) & 1u) ? e.y : 1.0f;
    out2[g2] = r;
}

// --- fallback: R5 two-kernel path (if ws unexpectedly small) ------------------

__global__ __launch_bounds__(NTHR)
void bin_lds_kernel(const float4* __restrict__ lm2,
                    unsigned int* __restrict__ regions) {
    __shared__ unsigned int mask[NWORDS];
    const int tid = threadIdx.x;
    #pragma unroll
    for (int w = tid; w < NWORDS; w += NTHR) mask[w] = 0u;
    __syncthreads();
    const int total = NBLK * NTHR;
    const int base  = blockIdx.x * NTHR + tid;
    float4 buf[ITERS];
    #pragma unroll
    for (int k = 0; k < ITERS; ++k) buf[k] = lm2[base + k * total];
    #pragma unroll
    for (int k = 0; k < ITERS; ++k) {
        float4 v = buf[k];
        int c0 = min((int)(v.x * 0.0625f), GRID_COLS - 1);
        int r0 = min((int)(v.y * 0.0625f), GRID_COLS - 1);
        int c1 = min((int)(v.z * 0.0625f), GRID_COLS - 1);
        int r1 = min((int)(v.w * 0.0625f), GRID_COLS - 1);
        unsigned int i0 = (unsigned int)(r0 * GRID_COLS + c0);
        unsigned int i1 = (unsigned int)(r1 * GRID_COLS + c1);
        atomicOr(&mask[i0 >> 5], 1u << (i0 & 31));
        atomicOr(&mask[i1 >> 5], 1u << (i1 & 31));
    }
    __syncthreads();
    unsigned int* dst = regions + (size_t)blockIdx.x * NWORDS;
    #pragma unroll
    for (int w = tid; w < NWORDS; w += NTHR) dst[w] = mask[w];
}

__global__ __launch_bounds__(256)
void merge_blend_kernel(const unsigned int* __restrict__ regions,
                        const float4* __restrict__ ew4,
                        float4* __restrict__ out4) {
    __shared__ unsigned int part[8][33];
    __shared__ unsigned int merged[32];
    const int t   = threadIdx.x;
    const int wl  = t & 31;
    const int seg = t >> 5;
    const int w   = blockIdx.x * 32 + wl;
    const unsigned int* p = regions + (size_t)seg * 32 * NWORDS + w;
    unsigned int m = 0u;
    #pragma unroll
    for (int bb = 0; bb < 32; ++bb) m |= p[(size_t)bb * NWORDS];
    part[seg][wl] = m;
    __syncthreads();
    if (t < 32) {
        unsigned int mm = part[0][t];
        #pragma unroll
        for (int s = 1; s < 8; ++s) mm |= part[s][t];
        merged[t] = mm;
    }
    __syncthreads();
    const int g4 = blockIdx.x * 256 + t;
    const unsigned int mw = merged[t >> 3];
    const int sh = (t & 7) * 4;
    float4 e = ew4[g4];
    float4 r;
    r.x = ((mw >> (sh + 0)) & 1u) ? e.x : 1.0f;
    r.y = ((mw >> (sh + 1)) & 1u) ? e.y : 1.0f;
    r.z = ((mw >> (sh + 2)) & 1u) ? e.z : 1.0f;
    r.w = ((mw >> (sh + 3)) & 1u) ? e.w : 1.0f;
    out4[g4] = r;
}

extern "C" void kernel_launch(void* const* d_in, const int* in_sizes, int n_in,
                              void* d_out, int out_size, void* d_ws, size_t ws_size,
                              hipStream_t stream) {
    const float4* lm2 = (const float4*)d_in[0];
    const float*  ew  = (const float*)d_in[1];
    float* out        = (float*)d_out;

    const size_t need = 4096 + (size_t)NBLK * NWORDS * sizeof(unsigned int); // 4K + 8MB

    if (ws_size >= need) {
        unsigned int* counter = (unsigned int*)d_ws;
        unsigned int* regions = (unsigned int*)((char*)d_ws + 4096);
        hipMemsetAsync(counter, 0, sizeof(unsigned int), stream);
        fused_kernel<<<NBLK, NTHR, 0, stream>>>(lm2, ew, out, regions, counter);
    } else {
        unsigned int* regions = (unsigned int*)d_ws;
        bin_lds_kernel<<<NBLK, NTHR, 0, stream>>>(lm2, regions);
        merge_blend_kernel<<<NWORDS / 32, 256, 0, stream>>>(
            regions, (const float4*)ew, (float4*)out);
    }
    (void)in_sizes; (void)n_in; (void)out_size;
}